// Round 2
// baseline (771.981 us; speedup 1.0000x reference)
//
#include <hip/hip_runtime.h>
#include <hip/hip_bf16.h>

using bf16 = __hip_bfloat16;
typedef __attribute__((ext_vector_type(4))) float f32x4;
typedef __attribute__((ext_vector_type(2))) float f32x2;
typedef __attribute__((ext_vector_type(8))) __bf16 bf16x8;
typedef __attribute__((ext_vector_type(4))) unsigned int u32x4;
typedef unsigned short u16;

#define LOG2E 1.4426950408889634f

__device__ __forceinline__ void gload_lds16(const void* g, void* l) {
  __builtin_amdgcn_global_load_lds((const __attribute__((address_space(1))) void*)g,
                                   (__attribute__((address_space(3))) void*)l, 16, 0, 0);
}

__device__ __forceinline__ bf16x8 lds_frag(const bf16* p) {
  u32x4 u = *(const u32x4*)p;
  return __builtin_bit_cast(bf16x8, u);
}

__device__ __forceinline__ u16 bf_bits(float v) {
  return __builtin_bit_cast(u16, __float2bfloat16(v));
}

// NT GEMM: C[m][n] = sum_k A[m][k]*B[n][k]. 128x128 tile, BK=32, 256 threads.
// AMODE: 0 = A bf16 global (hi[/lo] pair if SPLIT) via global_load_lds
//        1 = A fp32 global, stage-convert to bf16 hi(/lo) in LDS
//        2 = A fp32 scores, softmax folded during staging (SINGLE only)
// SPLIT: hi/lo bf16 emulation of fp32 (3 MFMA passes: Ah*Bh + Al*Bh + Ah*Bl)
// CMODE: 0 = bf16 C, 1 = bf16 pair (Ch,Cl), 2 = fp32 C
// BIAS: += bias[n] (fp32). COLMASK (CMODE2): masked cols -> -1e30.
// ROWMASK (CMODE0): row *= (mask!=0).
template<int AMODE, bool SPLIT, int CMODE, bool BIAS, bool COLMASK, bool ROWMASK>
__global__ __launch_bounds__(256, 2) void gemm_nt(
    const void* __restrict__ Ah_, const void* __restrict__ Al_, long lda, long strideA,
    const bf16* __restrict__ Bh_, const bf16* __restrict__ Bl_, long ldb, long strideB,
    void* __restrict__ Ch_, void* __restrict__ Cl_, long ldc, long strideC,
    int K,
    const float* __restrict__ bias,
    const int* __restrict__ maskp, long maskStride,
    const f32x2* __restrict__ stats, long statsStride)
{
  const int tid = threadIdx.x;
  const int lane15 = tid & 15;
  const int quad = (tid >> 4) & 3;
  const int wave = tid >> 6;
  const int wm = (wave >> 1) * 64;
  const int wn = (wave & 1) * 64;
  const long z = blockIdx.z;
  const long m0 = (long)blockIdx.y * 128;
  const long n0 = (long)blockIdx.x * 128;

  constexpr int KW = SPLIT ? 64 : 32;
  __shared__ alignas(16) bf16 As[128 * KW];
  __shared__ alignas(16) bf16 Bs[128 * KW];

  const bf16* Bbh = Bh_ + z * strideB;
  const bf16* Bbl = SPLIT ? (Bl_ + z * strideB) : nullptr;

  const bf16* Abh = nullptr; const bf16* Abl = nullptr;
  const float* Af = nullptr;
  if constexpr (AMODE == 0) {
    Abh = (const bf16*)Ah_ + z * strideA;
    if constexpr (SPLIT) Abl = (const bf16*)Al_ + z * strideA;
  } else {
    Af = (const float*)Ah_ + z * strideA;
  }

  // AMODE 1/2 staging roles: thread t -> row t/2, half t&1
  const int arow = tid >> 1;
  const int ahalf = tid & 1;
  const int aflip = arow & 1;
  const int aswz = (arow >> 1) & 3;
  float mlog2 = 0.f, rinv = 0.f;
  if constexpr (AMODE == 2) {
    f32x2 st = stats[z * statsStride + m0 + arow];
    mlog2 = st.x; rinv = st.y;
  }

  f32x4 acc[4][4];
  #pragma unroll
  for (int i = 0; i < 4; ++i)
    #pragma unroll
    for (int j = 0; j < 4; ++j) acc[i][j] = (f32x4){0.f, 0.f, 0.f, 0.f};

  for (int k0 = 0; k0 < K; k0 += 32) {
    __syncthreads();
    // ---- B staging (always bf16 global via global_load_lds) ----
    if constexpr (SPLIT) {
      #pragma unroll
      for (int r = 0; r < 4; ++r) {
        const int idx = r * 256 + tid, row = idx >> 3, slot = idx & 7;
        const int flip = row & 1, sw = (row >> 1) & 3;
        const int h = (slot >> 2) ^ flip, s = (slot & 3) ^ sw;
        const bf16* g = (h ? Bbl : Bbh) + (n0 + row) * ldb + k0 + s * 8;
        gload_lds16(g, &Bs[idx * 8]);
      }
    } else {
      #pragma unroll
      for (int r = 0; r < 2; ++r) {
        const int idx = r * 256 + tid, row = idx >> 2, slot = idx & 3;
        const int sw = (row >> 1) & 3;
        gload_lds16(Bbh + (n0 + row) * ldb + k0 + (slot ^ sw) * 8, &Bs[idx * 8]);
      }
    }
    // ---- A staging ----
    if constexpr (AMODE == 0) {
      if constexpr (SPLIT) {
        #pragma unroll
        for (int r = 0; r < 4; ++r) {
          const int idx = r * 256 + tid, row = idx >> 3, slot = idx & 7;
          const int flip = row & 1, sw = (row >> 1) & 3;
          const int h = (slot >> 2) ^ flip, s = (slot & 3) ^ sw;
          const bf16* g = (h ? Abl : Abh) + (m0 + row) * lda + k0 + s * 8;
          gload_lds16(g, &As[idx * 8]);
        }
      } else {
        #pragma unroll
        for (int r = 0; r < 2; ++r) {
          const int idx = r * 256 + tid, row = idx >> 2, slot = idx & 3;
          const int sw = (row >> 1) & 3;
          gload_lds16(Abh + (m0 + row) * lda + k0 + (slot ^ sw) * 8, &As[idx * 8]);
        }
      }
    } else if constexpr (AMODE == 1) {
      const float* src = Af + (m0 + arow) * lda + k0;
      #pragma unroll
      for (int ss = 0; ss < 2; ++ss) {
        const int s = ahalf * 2 + ss;
        float tv[8];
        *(f32x4*)tv       = *(const f32x4*)(src + s * 8);
        *(f32x4*)(tv + 4) = *(const f32x4*)(src + s * 8 + 4);
        u32x4 hi, lo;
        u16* ph = (u16*)&hi; u16* pl = (u16*)&lo;
        #pragma unroll
        for (int j = 0; j < 8; ++j) {
          bf16 hb = __float2bfloat16(tv[j]);
          ph[j] = __builtin_bit_cast(u16, hb);
          if constexpr (SPLIT) pl[j] = bf_bits(tv[j] - __bfloat162float(hb));
        }
        if constexpr (SPLIT) {
          const int sh = (aflip << 2) | (s ^ aswz);
          *(u32x4*)&As[arow * 64 + sh * 8] = hi;
          *(u32x4*)&As[arow * 64 + (sh ^ 4) * 8] = lo;
        } else {
          *(u32x4*)&As[arow * 32 + (s ^ aswz) * 8] = hi;
        }
      }
    } else {  // AMODE == 2: softmax staging (SINGLE)
      const float* src = Af + (m0 + arow) * lda + k0;
      #pragma unroll
      for (int ss = 0; ss < 2; ++ss) {
        const int s = ahalf * 2 + ss;
        const int g = s ^ aswz;
        float tv[8];
        *(f32x4*)tv       = *(const f32x4*)(src + g * 8);
        *(f32x4*)(tv + 4) = *(const f32x4*)(src + g * 8 + 4);
        u32x4 o; u16* po = (u16*)&o;
        #pragma unroll
        for (int j = 0; j < 8; ++j) {
          float p = exp2f(fmaf(tv[j], LOG2E, -mlog2)) * rinv;
          po[j] = bf_bits(p);
        }
        *(u32x4*)&As[arow * 32 + s * 8] = o;
      }
    }
    __syncthreads();

    const int swl = (lane15 >> 1) & 3;
    if constexpr (SPLIT) {
      const int eff = ((lane15 & 1) << 2) | (quad ^ swl);
      bf16x8 ah[4], al[4], bh[4], bl[4];
      #pragma unroll
      for (int t = 0; t < 4; ++t) {
        const int ar = (wm + t * 16 + lane15) * 64;
        const int br = (wn + t * 16 + lane15) * 64;
        ah[t] = lds_frag(&As[ar + eff * 8]);
        al[t] = lds_frag(&As[ar + (eff ^ 4) * 8]);
        bh[t] = lds_frag(&Bs[br + eff * 8]);
        bl[t] = lds_frag(&Bs[br + (eff ^ 4) * 8]);
      }
      #pragma unroll
      for (int i = 0; i < 4; ++i)
        #pragma unroll
        for (int j = 0; j < 4; ++j) {
          acc[i][j] = __builtin_amdgcn_mfma_f32_16x16x32_bf16(ah[i], bh[j], acc[i][j], 0, 0, 0);
          acc[i][j] = __builtin_amdgcn_mfma_f32_16x16x32_bf16(al[i], bh[j], acc[i][j], 0, 0, 0);
          acc[i][j] = __builtin_amdgcn_mfma_f32_16x16x32_bf16(ah[i], bl[j], acc[i][j], 0, 0, 0);
        }
    } else {
      const int eff = quad ^ swl;
      bf16x8 ah[4], bh[4];
      #pragma unroll
      for (int t = 0; t < 4; ++t) ah[t] = lds_frag(&As[(wm + t * 16 + lane15) * 32 + eff * 8]);
      #pragma unroll
      for (int t = 0; t < 4; ++t) bh[t] = lds_frag(&Bs[(wn + t * 16 + lane15) * 32 + eff * 8]);
      #pragma unroll
      for (int i = 0; i < 4; ++i)
        #pragma unroll
        for (int j = 0; j < 4; ++j)
          acc[i][j] = __builtin_amdgcn_mfma_f32_16x16x32_bf16(ah[i], bh[j], acc[i][j], 0, 0, 0);
    }
  }

  // C/D layout: col = lane&15, row = quad*4 + reg   [measured m89/m91]
  const long crow0 = m0 + wm + quad * 4;
  const long ccol0 = n0 + wn + lane15;
  float bv[4] = {0.f, 0.f, 0.f, 0.f};
  if constexpr (BIAS) {
    #pragma unroll
    for (int tn = 0; tn < 4; ++tn) bv[tn] = bias[ccol0 + tn * 16];
  }
  if constexpr (CMODE == 2) {
    float* C = (float*)Ch_ + z * strideC;
    #pragma unroll
    for (int tn = 0; tn < 4; ++tn) {
      const long col = ccol0 + tn * 16;
      bool keep = true;
      if constexpr (COLMASK) keep = (maskp[z * maskStride + col] != 0);
      #pragma unroll
      for (int tm = 0; tm < 4; ++tm) {
        const long row = crow0 + tm * 16;
        #pragma unroll
        for (int r = 0; r < 4; ++r) {
          float val = acc[tm][tn][r] + bv[tn];
          if constexpr (COLMASK) { if (!keep) val = -1e30f; }
          C[(row + r) * ldc + col] = val;
        }
      }
    }
  } else if constexpr (CMODE == 1) {
    bf16* Ch = (bf16*)Ch_ + z * strideC;
    bf16* Cl = (bf16*)Cl_ + z * strideC;
    #pragma unroll
    for (int tm = 0; tm < 4; ++tm) {
      const long row = crow0 + tm * 16;
      #pragma unroll
      for (int tn = 0; tn < 4; ++tn) {
        const long col = ccol0 + tn * 16;
        #pragma unroll
        for (int r = 0; r < 4; ++r) {
          float val = acc[tm][tn][r] + bv[tn];
          bf16 h = __float2bfloat16(val);
          Ch[(row + r) * ldc + col] = h;
          Cl[(row + r) * ldc + col] = __float2bfloat16(val - __bfloat162float(h));
        }
      }
    }
  } else {
    bf16* Ch = (bf16*)Ch_ + z * strideC;
    #pragma unroll
    for (int tm = 0; tm < 4; ++tm) {
      const long row = crow0 + tm * 16;
      float rm[4] = {1.f, 1.f, 1.f, 1.f};
      if constexpr (ROWMASK) {
        #pragma unroll
        for (int r = 0; r < 4; ++r)
          rm[r] = (maskp[z * maskStride + row + r] != 0) ? 1.f : 0.f;
      }
      #pragma unroll
      for (int tn = 0; tn < 4; ++tn) {
        const long col = ccol0 + tn * 16;
        #pragma unroll
        for (int r = 0; r < 4; ++r)
          Ch[(row + r) * ldc + col] = __float2bfloat16((acc[tm][tn][r] + bv[tn]) * rm[r]);
      }
    }
  }
}

// fp32 -> bf16 hi (+ optional lo residual), 8 elems/thread
__global__ __launch_bounds__(256) void cvt_kernel(
    const float* __restrict__ in, bf16* __restrict__ outH, bf16* __restrict__ outL, int n8)
{
  const int i = blockIdx.x * 256 + threadIdx.x;
  if (i >= n8) return;
  float tv[8];
  *(f32x4*)tv       = ((const f32x4*)in)[2 * i];
  *(f32x4*)(tv + 4) = ((const f32x4*)in)[2 * i + 1];
  u32x4 H, L;
  u16* ph = (u16*)&H; u16* pl = (u16*)&L;
  #pragma unroll
  for (int j = 0; j < 8; ++j) {
    bf16 hb = __float2bfloat16(tv[j]);
    ph[j] = __builtin_bit_cast(u16, hb);
    pl[j] = bf_bits(tv[j] - __bfloat162float(hb));
  }
  ((u32x4*)outH)[i] = H;
  if (outL) ((u32x4*)outL)[i] = L;
}

// per-row max(log2-scaled) & 1/sum(exp2) over fp32 score rows
__global__ __launch_bounds__(256) void row_stats_kernel(
    const float* __restrict__ S, f32x2* __restrict__ stats, int ncols)
{
  const long row = blockIdx.x;
  const float* p = S + row * (long)ncols;
  const int tid = threadIdx.x, lane = tid & 63, wave = tid >> 6;
  f32x4 a = *(const f32x4*)(p + tid * 8);
  f32x4 b = *(const f32x4*)(p + tid * 8 + 4);
  float mx = -3.0e38f;
  #pragma unroll
  for (int j = 0; j < 4; ++j) mx = fmaxf(mx, fmaxf(a[j], b[j]));
  #pragma unroll
  for (int o = 32; o > 0; o >>= 1) mx = fmaxf(mx, __shfl_xor(mx, o, 64));
  __shared__ float redm[4], reds[4];
  if (lane == 0) redm[wave] = mx;
  __syncthreads();
  mx = fmaxf(fmaxf(redm[0], redm[1]), fmaxf(redm[2], redm[3]));
  const float m2 = mx * LOG2E;
  float s = 0.f;
  #pragma unroll
  for (int j = 0; j < 4; ++j) {
    s += exp2f(fmaf(a[j], LOG2E, -m2));
    s += exp2f(fmaf(b[j], LOG2E, -m2));
  }
  #pragma unroll
  for (int o = 32; o > 0; o >>= 1) s += __shfl_xor(s, o, 64);
  if (lane == 0) reds[wave] = s;
  __syncthreads();
  if (tid == 0) {
    float tot = reds[0] + reds[1] + reds[2] + reds[3];
    stats[row] = (f32x2){m2, 1.0f / tot};
  }
}

// 64x64-tile bf16 transpose (raw u16)
__global__ __launch_bounds__(256) void transpose_kernel(
    const u16* __restrict__ in, u16* __restrict__ out, long rows, long cols)
{
  __shared__ alignas(16) u16 t[64][72];
  const long r0 = (long)blockIdx.x * 64, c0 = (long)blockIdx.y * 64;
  const int tid = threadIdx.x;
  const int rr = tid >> 3, cs = (tid & 7) * 8;
  #pragma unroll
  for (int i = 0; i < 2; ++i) {
    const int row = rr + i * 32;
    u32x4 v = *(const u32x4*)(in + (r0 + row) * cols + c0 + cs);
    *(u32x4*)&t[row][cs] = v;
  }
  __syncthreads();
  #pragma unroll
  for (int i = 0; i < 2; ++i) {
    const int oc = rr + i * 32;
    u32x4 o;
    u16* po = (u16*)&o;
    #pragma unroll
    for (int j = 0; j < 8; ++j) po[j] = t[cs + j][oc];
    *(u32x4*)(out + (c0 + oc) * rows + r0 + cs) = o;
  }
}

extern "C" void kernel_launch(void* const* d_in, const int* in_sizes, int n_in,
                              void* d_out, int out_size, void* d_ws, size_t ws_size,
                              hipStream_t stream) {
  const float* query = (const float*)d_in[0];
  const float* value = (const float*)d_in[1];
  const int*   mask  = (const int*)d_in[2];
  const float* q_w   = (const float*)d_in[3];
  const float* q_b   = (const float*)d_in[4];
  const float* k_w   = (const float*)d_in[5];
  const float* k_b   = (const float*)d_in[6];
  const float* v_w   = (const float*)d_in[7];
  const float* v_b   = (const float*)d_in[8];
  const float* fc_w  = (const float*)d_in[9];
  const float* fc_b  = (const float*)d_in[10];

  const long N = 2048, D = 768, M = 8 * N;
  const int WN = (int)(D * D), W8 = WN / 8;

  char* wp = (char*)d_ws;
  auto take = [&](size_t bytes) {
    char* p = wp;
    wp += (bytes + 255) & ~(size_t)255;
    return p;
  };
  bf16* Wqh = (bf16*)take((size_t)WN * 2);
  bf16* Wql = (bf16*)take((size_t)WN * 2);
  bf16* Wkh = (bf16*)take((size_t)WN * 2);
  bf16* Wkl = (bf16*)take((size_t)WN * 2);
  bf16* Wvh = (bf16*)take((size_t)WN * 2);
  bf16* Wfh = (bf16*)take((size_t)WN * 2);
  bf16* Qh = (bf16*)take((size_t)M * D * 2);
  bf16* Ql = (bf16*)take((size_t)M * D * 2);
  bf16* Kh = (bf16*)take((size_t)M * D * 2);
  bf16* Kl = (bf16*)take((size_t)M * D * 2);
  bf16* V  = (bf16*)take((size_t)M * D * 2);
  bf16* VT = (bf16*)take((size_t)M * D * 2);
  f32x2* st = (f32x2*)take((size_t)8 * N * sizeof(f32x2));
  bf16* merged = Qh;  // Qh dead per chunk after its S-GEMM

  const size_t perB = (size_t)N * N * sizeof(float);
  const size_t used = (size_t)(wp - (char*)d_ws);
  long rem = (long)ws_size - (long)used;
  int nb; float* S;
  if (rem >= (long)perB) {
    nb = (int)(rem / (long)perB);
    if (nb > 8) nb = 8;
    S = (float*)take((size_t)nb * perB);
  } else {
    nb = 1;
    S = (float*)V;  // V dead after transpose; 25.2 MB >= 16.8 MB
  }

  dim3 blk(256);

  cvt_kernel<<<dim3(288), blk, 0, stream>>>(q_w, Wqh, Wql, W8);
  cvt_kernel<<<dim3(288), blk, 0, stream>>>(k_w, Wkh, Wkl, W8);
  cvt_kernel<<<dim3(288), blk, 0, stream>>>(v_w, Wvh, nullptr, W8);
  cvt_kernel<<<dim3(288), blk, 0, stream>>>(fc_w, Wfh, nullptr, W8);

  // Q/K projections: split (hi/lo) for score accuracy; V: single
  gemm_nt<1, true, 1, true, false, false><<<dim3(6, 128, 1), blk, 0, stream>>>(
      query, nullptr, D, 0, Wqh, Wql, D, 0, Qh, Ql, D, 0, (int)D,
      q_b, nullptr, 0, nullptr, 0);
  gemm_nt<1, true, 1, true, false, false><<<dim3(6, 128, 1), blk, 0, stream>>>(
      value, nullptr, D, 0, Wkh, Wkl, D, 0, Kh, Kl, D, 0, (int)D,
      k_b, nullptr, 0, nullptr, 0);
  gemm_nt<1, false, 0, true, false, false><<<dim3(6, 128, 1), blk, 0, stream>>>(
      value, nullptr, D, 0, Wvh, nullptr, D, 0, V, nullptr, D, 0, (int)D,
      v_b, nullptr, 0, nullptr, 0);
  transpose_kernel<<<dim3(M / 64, D / 64, 1), blk, 0, stream>>>(
      (const u16*)V, (u16*)VT, M, D);

  for (int b0 = 0; b0 < 8; b0 += nb) {
    const int nz = (8 - b0 < nb) ? (8 - b0) : nb;
    // S = Q K^T (fp32, split-accurate), key mask -> -1e30
    gemm_nt<0, true, 2, false, true, false><<<dim3(16, 16, nz), blk, 0, stream>>>(
        Qh + (long)b0 * N * D, Ql + (long)b0 * N * D, D, N * D,
        Kh + (long)b0 * N * D, Kl + (long)b0 * N * D, D, N * D,
        S, nullptr, N, N * N, (int)N == 0 ? 0 : (int)D,
        nullptr, mask + (long)b0 * N, N, nullptr, 0);
    row_stats_kernel<<<dim3((unsigned)(nz * N)), blk, 0, stream>>>(S, st, (int)N);
    // merged = softmax(S) @ V, query-mask rows
    gemm_nt<2, false, 0, false, false, true><<<dim3(6, 16, nz), blk, 0, stream>>>(
        S, nullptr, N, N * N,
        VT + (long)b0 * N, nullptr, M, N,
        merged + (long)b0 * N * D, nullptr, D, N * D, (int)N,
        nullptr, mask + (long)b0 * N, N, st, N);
  }

  // out = merged @ fc_w^T + fc_b  (fp32 out)
  gemm_nt<0, false, 2, true, false, false><<<dim3(6, 128, 1), blk, 0, stream>>>(
      merged, nullptr, D, 0, Wfh, nullptr, D, 0, d_out, nullptr, D, 0, (int)D,
      fc_b, nullptr, 0, nullptr, 0);
}

// Round 3
// 652.965 us; speedup vs baseline: 1.1823x; 1.1823x over previous
//
#include <hip/hip_runtime.h>
#include <hip/hip_bf16.h>

using bf16 = __hip_bfloat16;
typedef __attribute__((ext_vector_type(4))) float f32x4;
typedef __attribute__((ext_vector_type(2))) float f32x2;
typedef __attribute__((ext_vector_type(8))) __bf16 bf16x8;
typedef __attribute__((ext_vector_type(4))) unsigned int u32x4;
typedef unsigned short u16;

#define LOG2E 1.4426950408889634f
// fixed softmax shift: p = exp(s - 48) = exp2(s*log2e - 48*log2e)
#define SHIFT2 69.24936192747498f

__device__ __forceinline__ void gload_lds16(const void* g, void* l) {
  __builtin_amdgcn_global_load_lds((const __attribute__((address_space(1))) void*)g,
                                   (__attribute__((address_space(3))) void*)l, 16, 0, 0);
}

__device__ __forceinline__ bf16x8 lds_frag(const bf16* p) {
  u32x4 u = *(const u32x4*)p;
  return __builtin_bit_cast(bf16x8, u);
}

__device__ __forceinline__ u16 bf_bits(float v) {
  return __builtin_bit_cast(u16, __float2bfloat16(v));
}

// NT GEMM: C[m][n] = sum_k A[m][k]*B[n][k]. 128x128 tile, BK=32, 256 threads.
// AMODE: 0 = A bf16 global (hi[/lo] pair if SPLIT) via global_load_lds
//        1 = A fp32 global, stage-convert to bf16 hi(/lo) in LDS
// SPLIT: hi/lo bf16 emulation of fp32 (3 MFMA passes)
// CMODE: 0 = bf16 C, 1 = bf16 pair (Ch,Cl), 2 = fp32 C,
//        3 = P-epilogue: bf16 exp(s-48) store + per-row sums to rowsum (atomic)
// BIAS: += bias[n] (fp32). COLMASK (CMODE3): masked cols -> P=0.
// ROWMASK (CMODE0): row *= (mask!=0). RSCALE (CMODE0): row *= 1/rowsum[row].
template<int AMODE, bool SPLIT, int CMODE, bool BIAS, bool COLMASK, bool ROWMASK, bool RSCALE>
__global__ __launch_bounds__(256, 2) void gemm_nt(
    const void* __restrict__ Ah_, const void* __restrict__ Al_, long lda, long strideA,
    const bf16* __restrict__ Bh_, const bf16* __restrict__ Bl_, long ldb, long strideB,
    void* __restrict__ Ch_, void* __restrict__ Cl_, long ldc, long strideC,
    int K,
    const float* __restrict__ bias,
    const int* __restrict__ maskp, long maskStride,
    float* __restrict__ rowsum, long rsStride)
{
  const int tid = threadIdx.x;
  const int lane15 = tid & 15;
  const int quad = (tid >> 4) & 3;
  const int wave = tid >> 6;
  const int wm = (wave >> 1) * 64;
  const int wn = (wave & 1) * 64;
  const long z = blockIdx.z;
  const long m0 = (long)blockIdx.y * 128;
  const long n0 = (long)blockIdx.x * 128;

  constexpr int KW = SPLIT ? 64 : 32;
  __shared__ alignas(16) bf16 As[128 * KW];
  __shared__ alignas(16) bf16 Bs[128 * KW];
  __shared__ float rowacc[128];

  const bf16* Bbh = Bh_ + z * strideB;
  const bf16* Bbl = SPLIT ? (Bl_ + z * strideB) : nullptr;

  const bf16* Abh = nullptr; const bf16* Abl = nullptr;
  const float* Af = nullptr;
  if constexpr (AMODE == 0) {
    Abh = (const bf16*)Ah_ + z * strideA;
    if constexpr (SPLIT) Abl = (const bf16*)Al_ + z * strideA;
  } else {
    Af = (const float*)Ah_ + z * strideA;
  }

  // AMODE 1 staging roles: thread t -> row t/2, half t&1
  const int arow = tid >> 1;
  const int ahalf = tid & 1;
  const int aflip = arow & 1;
  const int aswz = (arow >> 1) & 3;

  f32x4 acc[4][4];
  #pragma unroll
  for (int i = 0; i < 4; ++i)
    #pragma unroll
    for (int j = 0; j < 4; ++j) acc[i][j] = (f32x4){0.f, 0.f, 0.f, 0.f};

  for (int k0 = 0; k0 < K; k0 += 32) {
    __syncthreads();
    // ---- B staging ----
    if constexpr (SPLIT) {
      #pragma unroll
      for (int r = 0; r < 4; ++r) {
        const int idx = r * 256 + tid, row = idx >> 3, slot = idx & 7;
        const int flip = row & 1, sw = (row >> 1) & 3;
        const int h = (slot >> 2) ^ flip, s = (slot & 3) ^ sw;
        const bf16* g = (h ? Bbl : Bbh) + (n0 + row) * ldb + k0 + s * 8;
        gload_lds16(g, &Bs[idx * 8]);
      }
    } else {
      #pragma unroll
      for (int r = 0; r < 2; ++r) {
        const int idx = r * 256 + tid, row = idx >> 2, slot = idx & 3;
        const int sw = (row >> 1) & 3;
        gload_lds16(Bbh + (n0 + row) * ldb + k0 + (slot ^ sw) * 8, &Bs[idx * 8]);
      }
    }
    // ---- A staging ----
    if constexpr (AMODE == 0) {
      if constexpr (SPLIT) {
        #pragma unroll
        for (int r = 0; r < 4; ++r) {
          const int idx = r * 256 + tid, row = idx >> 3, slot = idx & 7;
          const int flip = row & 1, sw = (row >> 1) & 3;
          const int h = (slot >> 2) ^ flip, s = (slot & 3) ^ sw;
          const bf16* g = (h ? Abl : Abh) + (m0 + row) * lda + k0 + s * 8;
          gload_lds16(g, &As[idx * 8]);
        }
      } else {
        #pragma unroll
        for (int r = 0; r < 2; ++r) {
          const int idx = r * 256 + tid, row = idx >> 2, slot = idx & 3;
          const int sw = (row >> 1) & 3;
          gload_lds16(Abh + (m0 + row) * lda + k0 + (slot ^ sw) * 8, &As[idx * 8]);
        }
      }
    } else {  // AMODE == 1
      const float* src = Af + (m0 + arow) * lda + k0;
      #pragma unroll
      for (int ss = 0; ss < 2; ++ss) {
        const int s = ahalf * 2 + ss;
        float tv[8];
        *(f32x4*)tv       = *(const f32x4*)(src + s * 8);
        *(f32x4*)(tv + 4) = *(const f32x4*)(src + s * 8 + 4);
        u32x4 hi, lo;
        u16* ph = (u16*)&hi; u16* pl = (u16*)&lo;
        #pragma unroll
        for (int j = 0; j < 8; ++j) {
          bf16 hb = __float2bfloat16(tv[j]);
          ph[j] = __builtin_bit_cast(u16, hb);
          if constexpr (SPLIT) pl[j] = bf_bits(tv[j] - __bfloat162float(hb));
        }
        if constexpr (SPLIT) {
          const int sh = (aflip << 2) | (s ^ aswz);
          *(u32x4*)&As[arow * 64 + sh * 8] = hi;
          *(u32x4*)&As[arow * 64 + (sh ^ 4) * 8] = lo;
        } else {
          *(u32x4*)&As[arow * 32 + (s ^ aswz) * 8] = hi;
        }
      }
    }
    __syncthreads();

    const int swl = (lane15 >> 1) & 3;
    if constexpr (SPLIT) {
      const int eff = ((lane15 & 1) << 2) | (quad ^ swl);
      bf16x8 ah[4], al[4], bh[4], bl[4];
      #pragma unroll
      for (int t = 0; t < 4; ++t) {
        const int ar = (wm + t * 16 + lane15) * 64;
        const int br = (wn + t * 16 + lane15) * 64;
        ah[t] = lds_frag(&As[ar + eff * 8]);
        al[t] = lds_frag(&As[ar + (eff ^ 4) * 8]);
        bh[t] = lds_frag(&Bs[br + eff * 8]);
        bl[t] = lds_frag(&Bs[br + (eff ^ 4) * 8]);
      }
      #pragma unroll
      for (int i = 0; i < 4; ++i)
        #pragma unroll
        for (int j = 0; j < 4; ++j) {
          acc[i][j] = __builtin_amdgcn_mfma_f32_16x16x32_bf16(ah[i], bh[j], acc[i][j], 0, 0, 0);
          acc[i][j] = __builtin_amdgcn_mfma_f32_16x16x32_bf16(al[i], bh[j], acc[i][j], 0, 0, 0);
          acc[i][j] = __builtin_amdgcn_mfma_f32_16x16x32_bf16(ah[i], bl[j], acc[i][j], 0, 0, 0);
        }
    } else {
      const int eff = quad ^ swl;
      bf16x8 ah[4], bh[4];
      #pragma unroll
      for (int t = 0; t < 4; ++t) ah[t] = lds_frag(&As[(wm + t * 16 + lane15) * 32 + eff * 8]);
      #pragma unroll
      for (int t = 0; t < 4; ++t) bh[t] = lds_frag(&Bs[(wn + t * 16 + lane15) * 32 + eff * 8]);
      #pragma unroll
      for (int i = 0; i < 4; ++i)
        #pragma unroll
        for (int j = 0; j < 4; ++j)
          acc[i][j] = __builtin_amdgcn_mfma_f32_16x16x32_bf16(ah[i], bh[j], acc[i][j], 0, 0, 0);
    }
  }

  // C/D layout: col = lane&15, row = quad*4 + reg   [measured m89/m91]
  const long crow0 = m0 + wm + quad * 4;
  const long ccol0 = n0 + wn + lane15;

  if constexpr (CMODE == 3) {
    // P = exp(s - 48) as bf16 (masked cols -> 0), per-row sums -> rowsum (atomic)
    bf16* P = (bf16*)Ch_ + z * strideC;
    if (tid < 128) rowacc[tid] = 0.f;
    __syncthreads();
    bool keep[4];
    #pragma unroll
    for (int tn = 0; tn < 4; ++tn)
      keep[tn] = !COLMASK || (maskp[z * maskStride + ccol0 + tn * 16] != 0);
    #pragma unroll
    for (int tm = 0; tm < 4; ++tm) {
      #pragma unroll
      for (int r = 0; r < 4; ++r) {
        const long row = crow0 + tm * 16 + r;
        float rsum = 0.f;
        #pragma unroll
        for (int tn = 0; tn < 4; ++tn) {
          float p = keep[tn] ? exp2f(fmaf(acc[tm][tn][r], LOG2E, -SHIFT2)) : 0.f;
          bf16 pb = __float2bfloat16(p);
          P[row * ldc + ccol0 + tn * 16] = pb;
          rsum += __bfloat162float(pb);
        }
        atomicAdd(&rowacc[(int)(row - m0)], rsum);
      }
    }
    __syncthreads();
    if (tid < 128) atomicAdd(&rowsum[z * rsStride + m0 + tid], rowacc[tid]);
    return;
  }

  float bv[4] = {0.f, 0.f, 0.f, 0.f};
  if constexpr (BIAS) {
    #pragma unroll
    for (int tn = 0; tn < 4; ++tn) bv[tn] = bias[ccol0 + tn * 16];
  }
  if constexpr (CMODE == 2) {
    float* C = (float*)Ch_ + z * strideC;
    #pragma unroll
    for (int tn = 0; tn < 4; ++tn) {
      const long col = ccol0 + tn * 16;
      #pragma unroll
      for (int tm = 0; tm < 4; ++tm) {
        const long row = crow0 + tm * 16;
        #pragma unroll
        for (int r = 0; r < 4; ++r)
          C[(row + r) * ldc + col] = acc[tm][tn][r] + bv[tn];
      }
    }
  } else if constexpr (CMODE == 1) {
    bf16* Ch = (bf16*)Ch_ + z * strideC;
    bf16* Cl = (bf16*)Cl_ + z * strideC;
    #pragma unroll
    for (int tm = 0; tm < 4; ++tm) {
      const long row = crow0 + tm * 16;
      #pragma unroll
      for (int tn = 0; tn < 4; ++tn) {
        const long col = ccol0 + tn * 16;
        #pragma unroll
        for (int r = 0; r < 4; ++r) {
          float val = acc[tm][tn][r] + bv[tn];
          bf16 h = __float2bfloat16(val);
          Ch[(row + r) * ldc + col] = h;
          Cl[(row + r) * ldc + col] = __float2bfloat16(val - __bfloat162float(h));
        }
      }
    }
  } else {
    bf16* Ch = (bf16*)Ch_ + z * strideC;
    #pragma unroll
    for (int tm = 0; tm < 4; ++tm) {
      const long row = crow0 + tm * 16;
      float rm[4];
      #pragma unroll
      for (int r = 0; r < 4; ++r) {
        float f = 1.f;
        if constexpr (ROWMASK) f = (maskp[z * maskStride + row + r] != 0) ? 1.f : 0.f;
        if constexpr (RSCALE)  f *= 1.0f / rowsum[z * rsStride + row + r];
        rm[r] = f;
      }
      #pragma unroll
      for (int tn = 0; tn < 4; ++tn) {
        const long col = ccol0 + tn * 16;
        #pragma unroll
        for (int r = 0; r < 4; ++r)
          Ch[(row + r) * ldc + col] = __float2bfloat16((acc[tm][tn][r] + bv[tn]) * rm[r]);
      }
    }
  }
}

// fp32 -> bf16 hi (+ optional lo residual), 8 elems/thread
__global__ __launch_bounds__(256) void cvt_kernel(
    const float* __restrict__ in, bf16* __restrict__ outH, bf16* __restrict__ outL, int n8)
{
  const int i = blockIdx.x * 256 + threadIdx.x;
  if (i >= n8) return;
  float tv[8];
  *(f32x4*)tv       = ((const f32x4*)in)[2 * i];
  *(f32x4*)(tv + 4) = ((const f32x4*)in)[2 * i + 1];
  u32x4 H, L;
  u16* ph = (u16*)&H; u16* pl = (u16*)&L;
  #pragma unroll
  for (int j = 0; j < 8; ++j) {
    bf16 hb = __float2bfloat16(tv[j]);
    ph[j] = __builtin_bit_cast(u16, hb);
    pl[j] = bf_bits(tv[j] - __bfloat162float(hb));
  }
  ((u32x4*)outH)[i] = H;
  if (outL) ((u32x4*)outL)[i] = L;
}

// 64x64-tile bf16 transpose (raw u16)
__global__ __launch_bounds__(256) void transpose_kernel(
    const u16* __restrict__ in, u16* __restrict__ out, long rows, long cols)
{
  __shared__ alignas(16) u16 t[64][72];
  const long r0 = (long)blockIdx.x * 64, c0 = (long)blockIdx.y * 64;
  const int tid = threadIdx.x;
  const int rr = tid >> 3, cs = (tid & 7) * 8;
  #pragma unroll
  for (int i = 0; i < 2; ++i) {
    const int row = rr + i * 32;
    u32x4 v = *(const u32x4*)(in + (r0 + row) * cols + c0 + cs);
    *(u32x4*)&t[row][cs] = v;
  }
  __syncthreads();
  #pragma unroll
  for (int i = 0; i < 2; ++i) {
    const int oc = rr + i * 32;
    u32x4 o;
    u16* po = (u16*)&o;
    #pragma unroll
    for (int j = 0; j < 8; ++j) po[j] = t[cs + j][oc];
    *(u32x4*)(out + (c0 + oc) * rows + r0 + cs) = o;
  }
}

extern "C" void kernel_launch(void* const* d_in, const int* in_sizes, int n_in,
                              void* d_out, int out_size, void* d_ws, size_t ws_size,
                              hipStream_t stream) {
  const float* query = (const float*)d_in[0];
  const float* value = (const float*)d_in[1];
  const int*   mask  = (const int*)d_in[2];
  const float* q_w   = (const float*)d_in[3];
  const float* q_b   = (const float*)d_in[4];
  const float* k_w   = (const float*)d_in[5];
  const float* k_b   = (const float*)d_in[6];
  const float* v_w   = (const float*)d_in[7];
  const float* v_b   = (const float*)d_in[8];
  const float* fc_w  = (const float*)d_in[9];
  const float* fc_b  = (const float*)d_in[10];

  const long N = 2048, D = 768, M = 8 * N;
  const int WN = (int)(D * D), W8 = WN / 8;

  char* wp = (char*)d_ws;
  auto take = [&](size_t bytes) {
    char* p = wp;
    wp += (bytes + 255) & ~(size_t)255;
    return p;
  };
  bf16* Wqh = (bf16*)take((size_t)WN * 2);
  bf16* Wql = (bf16*)take((size_t)WN * 2);
  bf16* Wkh = (bf16*)take((size_t)WN * 2);
  bf16* Wkl = (bf16*)take((size_t)WN * 2);
  bf16* Wvh = (bf16*)take((size_t)WN * 2);
  bf16* Wfh = (bf16*)take((size_t)WN * 2);
  bf16* Qh = (bf16*)take((size_t)M * D * 2);
  bf16* Ql = (bf16*)take((size_t)M * D * 2);
  bf16* Kh = (bf16*)take((size_t)M * D * 2);
  bf16* Kl = (bf16*)take((size_t)M * D * 2);
  bf16* V  = (bf16*)take((size_t)M * D * 2);
  bf16* VT = (bf16*)take((size_t)M * D * 2);
  float* rowsum = (float*)take((size_t)8 * N * sizeof(float));
  bf16* merged = Qh;  // Qh dead per chunk after its S-GEMM

  const size_t perB = (size_t)N * N * 2;  // bf16 P per batch
  const size_t used = (size_t)(wp - (char*)d_ws);
  long rem = (long)ws_size - (long)used;
  int nb; bf16* P;
  if (rem >= (long)perB) {
    nb = (int)(rem / (long)perB);
    if (nb > 8) nb = 8;
    P = (bf16*)take((size_t)nb * perB);
  } else {
    nb = 3;               // V dead after transpose: 25.17 MB = exactly 3 * 8.39 MB
    P = V;
  }

  dim3 blk(256);

  cvt_kernel<<<dim3(288), blk, 0, stream>>>(q_w, Wqh, Wql, W8);
  cvt_kernel<<<dim3(288), blk, 0, stream>>>(k_w, Wkh, Wkl, W8);
  cvt_kernel<<<dim3(288), blk, 0, stream>>>(v_w, Wvh, nullptr, W8);
  cvt_kernel<<<dim3(288), blk, 0, stream>>>(fc_w, Wfh, nullptr, W8);

  // Q/K projections: split (hi/lo) for score accuracy; V: single
  gemm_nt<1, true, 1, true, false, false, false><<<dim3(6, 128, 1), blk, 0, stream>>>(
      query, nullptr, D, 0, Wqh, Wql, D, 0, Qh, Ql, D, 0, (int)D,
      q_b, nullptr, 0, nullptr, 0);
  gemm_nt<1, true, 1, true, false, false, false><<<dim3(6, 128, 1), blk, 0, stream>>>(
      value, nullptr, D, 0, Wkh, Wkl, D, 0, Kh, Kl, D, 0, (int)D,
      k_b, nullptr, 0, nullptr, 0);
  gemm_nt<1, false, 0, true, false, false, false><<<dim3(6, 128, 1), blk, 0, stream>>>(
      value, nullptr, D, 0, Wvh, nullptr, D, 0, V, nullptr, D, 0, (int)D,
      v_b, nullptr, 0, nullptr, 0);
  transpose_kernel<<<dim3(M / 64, D / 64, 1), blk, 0, stream>>>(
      (const u16*)V, (u16*)VT, M, D);

  hipMemsetAsync(rowsum, 0, (size_t)8 * N * sizeof(float), stream);

  for (int b0 = 0; b0 < 8; b0 += nb) {
    const int nz = (8 - b0 < nb) ? (8 - b0) : nb;
    // P = exp(Q K^T - 48) bf16 (split-accurate scores), key mask -> 0, rowsums atomic
    gemm_nt<0, true, 3, false, true, false, false><<<dim3(16, 16, nz), blk, 0, stream>>>(
        Qh + (long)b0 * N * D, Ql + (long)b0 * N * D, D, N * D,
        Kh + (long)b0 * N * D, Kl + (long)b0 * N * D, D, N * D,
        P, nullptr, N, N * N, (int)D,
        nullptr, mask + (long)b0 * N, N, rowsum + (long)b0 * N, N);
    // merged = (P @ V) * (1/rowsum) * query-mask
    gemm_nt<0, false, 0, false, false, true, true><<<dim3(6, 16, nz), blk, 0, stream>>>(
        P, nullptr, N, N * N,
        VT + (long)b0 * N, nullptr, M, N,
        merged + (long)b0 * N * D, nullptr, D, N * D, (int)N,
        nullptr, mask + (long)b0 * N, N, rowsum + (long)b0 * N, N);
  }

  // out = merged @ fc_w^T + fc_b  (fp32 out)
  gemm_nt<0, false, 2, true, false, false, false><<<dim3(6, 128, 1), blk, 0, stream>>>(
      merged, nullptr, D, 0, Wfh, nullptr, D, 0, d_out, nullptr, D, 0, (int)D,
      fc_b, nullptr, 0, nullptr, 0);
}

// Round 4
// 456.102 us; speedup vs baseline: 1.6926x; 1.4316x over previous
//
#include <hip/hip_runtime.h>
#include <hip/hip_bf16.h>

using bf16 = __hip_bfloat16;
typedef __attribute__((ext_vector_type(4))) float f32x4;
typedef __attribute__((ext_vector_type(8))) __bf16 bf16x8;
typedef __attribute__((ext_vector_type(4))) unsigned int u32x4;
typedef unsigned short u16;

#define LOG2E 1.4426950408889634f
// fixed softmax shift: p = exp(s - 48) = exp2(s*log2e - 48*log2e)
#define SHIFT2 69.24936192747498f

__device__ __forceinline__ void gload_lds16(const void* g, void* l) {
  __builtin_amdgcn_global_load_lds((const __attribute__((address_space(1))) void*)g,
                                   (__attribute__((address_space(3))) void*)l, 16, 0, 0);
}

__device__ __forceinline__ bf16x8 lds_frag(const bf16* p) {
  u32x4 u = *(const u32x4*)p;
  return __builtin_bit_cast(bf16x8, u);
}

__device__ __forceinline__ u16 bf_bits(float v) {
  return __builtin_bit_cast(u16, __float2bfloat16(v));
}

// NT GEMM: C[m][n] = sum_k A[m][k]*B[n][k]. 128x128 tile, BK=32, 256 threads.
// AMODE: 0 = A bf16 global (hi[/lo] if SPLIT) via global_load_lds
//        1 = A fp32 global, stage-convert to bf16 hi(/lo) in LDS
// SPLIT: hi/lo bf16 emulation of fp32 (3 MFMA passes)
// CMODE: 0 = bf16 C, 1 = bf16 pair (Ch,Cl), 2 = fp32 C,
//        3 = P-epilogue: bf16 exp(s-48), cols>=cnt -> 0, row sums -> rowsum (atomic)
// BIAS: += bias[n]. RSCALE (CMODE0): row *= 1/rowsum[row].
// MGATHER (AMODE1): A row gathered via idxp. CSCAT (CMODE2): C row scattered via idxp, rows>=cnt skipped.
// RAGK: K = pad128(cnt[z]). NCHECK: early-exit n0 >= cnt[z]. cntp!=null: early-exit m0 >= cnt[z].
template<int AMODE, bool SPLIT, int CMODE, bool BIAS, bool RSCALE,
         bool MGATHER, bool CSCAT, bool RAGK, bool NCHECK>
__global__ __launch_bounds__(256, 2) void gemm_nt(
    const void* __restrict__ Ah_, const void* __restrict__ Al_, long lda, long strideA,
    const bf16* __restrict__ Bh_, const bf16* __restrict__ Bl_, long ldb, long strideB,
    void* __restrict__ Ch_, void* __restrict__ Cl_, long ldc, long strideC,
    int Kparam,
    const float* __restrict__ bias,
    float* __restrict__ rowsum, long rsStride,
    const int* __restrict__ idxp, const int* __restrict__ cntp)
{
  const int tid = threadIdx.x;
  const int lane15 = tid & 15;
  const int quad = (tid >> 4) & 3;
  const int wave = tid >> 6;
  const int wm = (wave >> 1) * 64;
  const int wn = (wave & 1) * 64;
  const long z = blockIdx.z;
  const long m0 = (long)blockIdx.y * 128;
  const long n0 = (long)blockIdx.x * 128;

  int cnt = 1 << 30;
  if (cntp) {
    cnt = cntp[z];
    if (m0 >= cnt) return;
    if constexpr (NCHECK) { if (n0 >= cnt) return; }
  }
  const int K = RAGK ? ((cnt + 127) & ~127) : Kparam;

  constexpr int KW = SPLIT ? 64 : 32;
  __shared__ alignas(16) bf16 As[128 * KW];
  __shared__ alignas(16) bf16 Bs[128 * KW];
  __shared__ float rowacc[128];

  const bf16* Bbh = Bh_ + z * strideB;
  const bf16* Bbl = SPLIT ? (Bl_ + z * strideB) : nullptr;

  const bf16* Abh = nullptr; const bf16* Abl = nullptr;
  const float* Af = nullptr;
  if constexpr (AMODE == 0) {
    Abh = (const bf16*)Ah_ + z * strideA;
    if constexpr (SPLIT) Abl = (const bf16*)Al_ + z * strideA;
  } else {
    Af = (const float*)Ah_ + z * strideA;
  }

  // AMODE 1 staging roles: thread t -> row t/2, half t&1
  const int arow = tid >> 1;
  const int ahalf = tid & 1;
  const int aflip = arow & 1;
  const int aswz = (arow >> 1) & 3;
  long agrow = m0 + arow;
  if constexpr (AMODE == 1 && MGATHER) agrow = idxp[z * 2048 + m0 + arow];

  f32x4 acc[4][4];
  #pragma unroll
  for (int i = 0; i < 4; ++i)
    #pragma unroll
    for (int j = 0; j < 4; ++j) acc[i][j] = (f32x4){0.f, 0.f, 0.f, 0.f};

  for (int k0 = 0; k0 < K; k0 += 32) {
    __syncthreads();
    // ---- B staging ----
    if constexpr (SPLIT) {
      #pragma unroll
      for (int r = 0; r < 4; ++r) {
        const int idx = r * 256 + tid, row = idx >> 3, slot = idx & 7;
        const int flip = row & 1, sw = (row >> 1) & 3;
        const int h = (slot >> 2) ^ flip, s = (slot & 3) ^ sw;
        const bf16* g = (h ? Bbl : Bbh) + (n0 + row) * ldb + k0 + s * 8;
        gload_lds16(g, &Bs[idx * 8]);
      }
    } else {
      #pragma unroll
      for (int r = 0; r < 2; ++r) {
        const int idx = r * 256 + tid, row = idx >> 2, slot = idx & 3;
        const int sw = (row >> 1) & 3;
        gload_lds16(Bbh + (n0 + row) * ldb + k0 + (slot ^ sw) * 8, &Bs[idx * 8]);
      }
    }
    // ---- A staging ----
    if constexpr (AMODE == 0) {
      if constexpr (SPLIT) {
        #pragma unroll
        for (int r = 0; r < 4; ++r) {
          const int idx = r * 256 + tid, row = idx >> 3, slot = idx & 7;
          const int flip = row & 1, sw = (row >> 1) & 3;
          const int h = (slot >> 2) ^ flip, s = (slot & 3) ^ sw;
          const bf16* g = (h ? Abl : Abh) + (m0 + row) * lda + k0 + s * 8;
          gload_lds16(g, &As[idx * 8]);
        }
      } else {
        #pragma unroll
        for (int r = 0; r < 2; ++r) {
          const int idx = r * 256 + tid, row = idx >> 2, slot = idx & 3;
          const int sw = (row >> 1) & 3;
          gload_lds16(Abh + (m0 + row) * lda + k0 + (slot ^ sw) * 8, &As[idx * 8]);
        }
      }
    } else {  // AMODE == 1 (optionally gathered)
      const float* src = Af + agrow * lda + k0;
      #pragma unroll
      for (int ss = 0; ss < 2; ++ss) {
        const int s = ahalf * 2 + ss;
        float tv[8];
        *(f32x4*)tv       = *(const f32x4*)(src + s * 8);
        *(f32x4*)(tv + 4) = *(const f32x4*)(src + s * 8 + 4);
        u32x4 hi, lo;
        u16* ph = (u16*)&hi; u16* pl = (u16*)&lo;
        #pragma unroll
        for (int j = 0; j < 8; ++j) {
          bf16 hb = __float2bfloat16(tv[j]);
          ph[j] = __builtin_bit_cast(u16, hb);
          if constexpr (SPLIT) pl[j] = bf_bits(tv[j] - __bfloat162float(hb));
        }
        if constexpr (SPLIT) {
          const int sh = (aflip << 2) | (s ^ aswz);
          *(u32x4*)&As[arow * 64 + sh * 8] = hi;
          *(u32x4*)&As[arow * 64 + (sh ^ 4) * 8] = lo;
        } else {
          *(u32x4*)&As[arow * 32 + (s ^ aswz) * 8] = hi;
        }
      }
    }
    __syncthreads();

    const int swl = (lane15 >> 1) & 3;
    if constexpr (SPLIT) {
      const int eff = ((lane15 & 1) << 2) | (quad ^ swl);
      bf16x8 ah[4], al[4], bh[4], bl[4];
      #pragma unroll
      for (int t = 0; t < 4; ++t) {
        const int ar = (wm + t * 16 + lane15) * 64;
        const int br = (wn + t * 16 + lane15) * 64;
        ah[t] = lds_frag(&As[ar + eff * 8]);
        al[t] = lds_frag(&As[ar + (eff ^ 4) * 8]);
        bh[t] = lds_frag(&Bs[br + eff * 8]);
        bl[t] = lds_frag(&Bs[br + (eff ^ 4) * 8]);
      }
      #pragma unroll
      for (int i = 0; i < 4; ++i)
        #pragma unroll
        for (int j = 0; j < 4; ++j) {
          acc[i][j] = __builtin_amdgcn_mfma_f32_16x16x32_bf16(ah[i], bh[j], acc[i][j], 0, 0, 0);
          acc[i][j] = __builtin_amdgcn_mfma_f32_16x16x32_bf16(al[i], bh[j], acc[i][j], 0, 0, 0);
          acc[i][j] = __builtin_amdgcn_mfma_f32_16x16x32_bf16(ah[i], bl[j], acc[i][j], 0, 0, 0);
        }
    } else {
      const int eff = quad ^ swl;
      bf16x8 ah[4], bh[4];
      #pragma unroll
      for (int t = 0; t < 4; ++t) ah[t] = lds_frag(&As[(wm + t * 16 + lane15) * 32 + eff * 8]);
      #pragma unroll
      for (int t = 0; t < 4; ++t) bh[t] = lds_frag(&Bs[(wn + t * 16 + lane15) * 32 + eff * 8]);
      #pragma unroll
      for (int i = 0; i < 4; ++i)
        #pragma unroll
        for (int j = 0; j < 4; ++j)
          acc[i][j] = __builtin_amdgcn_mfma_f32_16x16x32_bf16(ah[i], bh[j], acc[i][j], 0, 0, 0);
    }
  }

  // C/D layout: col = lane&15, row = quad*4 + reg   [measured m89/m91]
  const long crow0 = m0 + wm + quad * 4;
  const long ccol0 = n0 + wn + lane15;

  if constexpr (CMODE == 3) {
    // P = exp(s - 48) as bf16 (cols >= cnt -> 0), per-row sums -> rowsum (atomic)
    bf16* P = (bf16*)Ch_ + z * strideC;
    if (tid < 128) rowacc[tid] = 0.f;
    __syncthreads();
    bool keep[4];
    #pragma unroll
    for (int tn = 0; tn < 4; ++tn) keep[tn] = (ccol0 + tn * 16) < cnt;
    #pragma unroll
    for (int tm = 0; tm < 4; ++tm) {
      #pragma unroll
      for (int r = 0; r < 4; ++r) {
        const long row = crow0 + tm * 16 + r;
        float rsum = 0.f;
        #pragma unroll
        for (int tn = 0; tn < 4; ++tn) {
          float p = keep[tn] ? exp2f(fmaf(acc[tm][tn][r], LOG2E, -SHIFT2)) : 0.f;
          bf16 pb = __float2bfloat16(p);
          P[row * ldc + ccol0 + tn * 16] = pb;
          rsum += __bfloat162float(pb);
        }
        atomicAdd(&rowacc[(int)(row - m0)], rsum);
      }
    }
    __syncthreads();
    if (tid < 128) atomicAdd(&rowsum[z * rsStride + m0 + tid], rowacc[tid]);
    return;
  }

  float bv[4] = {0.f, 0.f, 0.f, 0.f};
  if constexpr (BIAS) {
    #pragma unroll
    for (int tn = 0; tn < 4; ++tn) bv[tn] = bias[ccol0 + tn * 16];
  }
  if constexpr (CMODE == 2) {
    float* C = (float*)Ch_ + z * strideC;
    #pragma unroll
    for (int tm = 0; tm < 4; ++tm) {
      #pragma unroll
      for (int r = 0; r < 4; ++r) {
        const long row = crow0 + tm * 16 + r;
        long orow = row;
        bool doStore = true;
        if constexpr (CSCAT) {
          doStore = row < cnt;
          orow = doStore ? (long)idxp[z * 2048 + row] : 0;
        }
        if (doStore) {
          #pragma unroll
          for (int tn = 0; tn < 4; ++tn)
            C[orow * ldc + ccol0 + tn * 16] = acc[tm][tn][r] + bv[tn];
        }
      }
    }
  } else if constexpr (CMODE == 1) {
    bf16* Ch = (bf16*)Ch_ + z * strideC;
    bf16* Cl = (bf16*)Cl_ + z * strideC;
    #pragma unroll
    for (int tm = 0; tm < 4; ++tm) {
      const long row = crow0 + tm * 16;
      #pragma unroll
      for (int tn = 0; tn < 4; ++tn) {
        const long col = ccol0 + tn * 16;
        #pragma unroll
        for (int r = 0; r < 4; ++r) {
          float val = acc[tm][tn][r] + bv[tn];
          bf16 h = __float2bfloat16(val);
          Ch[(row + r) * ldc + col] = h;
          Cl[(row + r) * ldc + col] = __float2bfloat16(val - __bfloat162float(h));
        }
      }
    }
  } else {
    bf16* Ch = (bf16*)Ch_ + z * strideC;
    #pragma unroll
    for (int tm = 0; tm < 4; ++tm) {
      const long row = crow0 + tm * 16;
      float rm[4];
      #pragma unroll
      for (int r = 0; r < 4; ++r) {
        float f = 1.f;
        if constexpr (RSCALE) f = 1.0f / rowsum[z * rsStride + row + r];
        rm[r] = f;
      }
      #pragma unroll
      for (int tn = 0; tn < 4; ++tn) {
        const long col = ccol0 + tn * 16;
        #pragma unroll
        for (int r = 0; r < 4; ++r)
          Ch[(row + r) * ldc + col] = __float2bfloat16((acc[tm][tn][r] + bv[tn]) * rm[r]);
      }
    }
  }
}

// per-batch compaction: idx[z][0..cnt) = positions with mask!=0; tail filled with last valid
__global__ __launch_bounds__(256) void compact_kernel(
    const int* __restrict__ mask, int* __restrict__ idx, int* __restrict__ cnt)
{
  const int z = blockIdx.x, tid = threadIdx.x;
  const int* m = mask + (long)z * 2048;
  int* id = idx + (long)z * 2048;
  int v[8]; int c = 0;
  #pragma unroll
  for (int j = 0; j < 8; ++j) { v[j] = m[tid * 8 + j]; c += (v[j] != 0) ? 1 : 0; }
  __shared__ int sc[256];
  sc[tid] = c;
  __syncthreads();
  for (int off = 1; off < 256; off <<= 1) {
    int y = 0;
    if (tid >= off) y = sc[tid - off];
    __syncthreads();
    if (tid >= off) sc[tid] += y;
    __syncthreads();
  }
  int k = sc[tid] - c;
  #pragma unroll
  for (int j = 0; j < 8; ++j)
    if (v[j]) id[k++] = tid * 8 + j;
  __syncthreads();
  const int tot = sc[255];
  if (tid == 0) cnt[z] = tot;
  const int last = id[tot - 1];
  for (int i = tot + tid; i < 2048; i += 256) id[i] = last;
}

// all 4 weight conversions in one launch (y selects matrix)
__global__ __launch_bounds__(256) void cvt4_kernel(
    const float* __restrict__ qw, const float* __restrict__ kw,
    const float* __restrict__ vw, const float* __restrict__ fw,
    bf16* __restrict__ Wqh, bf16* __restrict__ Wql,
    bf16* __restrict__ Wkh, bf16* __restrict__ Wkl,
    bf16* __restrict__ Wvh, bf16* __restrict__ Wfh, int n8)
{
  const int i = blockIdx.x * 256 + threadIdx.x;
  if (i >= n8) return;
  const float* in; bf16* oh; bf16* ol = nullptr;
  switch (blockIdx.y) {
    case 0:  in = qw; oh = Wqh; ol = Wql; break;
    case 1:  in = kw; oh = Wkh; ol = Wkl; break;
    case 2:  in = vw; oh = Wvh; break;
    default: in = fw; oh = Wfh; break;
  }
  float tv[8];
  *(f32x4*)tv       = ((const f32x4*)in)[2 * i];
  *(f32x4*)(tv + 4) = ((const f32x4*)in)[2 * i + 1];
  u32x4 H, L;
  u16* ph = (u16*)&H; u16* pl = (u16*)&L;
  #pragma unroll
  for (int j = 0; j < 8; ++j) {
    bf16 hb = __float2bfloat16(tv[j]);
    ph[j] = __builtin_bit_cast(u16, hb);
    pl[j] = bf_bits(tv[j] - __bfloat162float(hb));
  }
  ((u32x4*)oh)[i] = H;
  if (ol) ((u32x4*)ol)[i] = L;
}

// d_out[row][col] = fc_b[col] for all rows (valid rows overwritten by fc GEMM)
__global__ __launch_bounds__(256) void bias_fill_kernel(
    float* __restrict__ out, const float* __restrict__ fc_b)
{
  const long i = (long)blockIdx.x * 256 + threadIdx.x;  // f32x4 index
  const int col4 = (int)(i % 192);
  ((f32x4*)out)[i] = *(const f32x4*)(fc_b + col4 * 4);
}

// per-batch 64x64-tile bf16 transpose: V[z][r][c] -> VT[z][c][r]; skips r0 >= pad128(cnt)
__global__ __launch_bounds__(256) void transpose_kernel(
    const u16* __restrict__ in, u16* __restrict__ out, const int* __restrict__ cnt)
{
  const long z = blockIdx.z;
  const long r0 = (long)blockIdx.x * 64, c0 = (long)blockIdx.y * 64;
  const int kb = (cnt[z] + 127) & ~127;
  if (r0 >= kb) return;
  __shared__ alignas(16) u16 t[64][72];
  const u16* inz = in + z * 2048 * 768;
  u16* outz = out + z * 768 * 2048;
  const int tid = threadIdx.x;
  const int rr = tid >> 3, cs = (tid & 7) * 8;
  #pragma unroll
  for (int i = 0; i < 2; ++i) {
    const int row = rr + i * 32;
    u32x4 v = *(const u32x4*)(inz + (r0 + row) * 768 + c0 + cs);
    *(u32x4*)&t[row][cs] = v;
  }
  __syncthreads();
  #pragma unroll
  for (int i = 0; i < 2; ++i) {
    const int oc = rr + i * 32;
    u32x4 o;
    u16* po = (u16*)&o;
    #pragma unroll
    for (int j = 0; j < 8; ++j) po[j] = t[cs + j][oc];
    *(u32x4*)(outz + (c0 + oc) * 2048 + r0 + cs) = o;
  }
}

extern "C" void kernel_launch(void* const* d_in, const int* in_sizes, int n_in,
                              void* d_out, int out_size, void* d_ws, size_t ws_size,
                              hipStream_t stream) {
  const float* query = (const float*)d_in[0];
  const float* value = (const float*)d_in[1];
  const int*   mask  = (const int*)d_in[2];
  const float* q_w   = (const float*)d_in[3];
  const float* q_b   = (const float*)d_in[4];
  const float* k_w   = (const float*)d_in[5];
  const float* k_b   = (const float*)d_in[6];
  const float* v_w   = (const float*)d_in[7];
  const float* v_b   = (const float*)d_in[8];
  const float* fc_w  = (const float*)d_in[9];
  const float* fc_b  = (const float*)d_in[10];

  const long N = 2048, D = 768;
  const long BD = N * D;          // per-batch row-block (2048x768)
  const int WN = (int)(D * D), W8 = WN / 8;

  char* wp = (char*)d_ws;
  auto take = [&](size_t bytes) {
    char* p = wp;
    wp += (bytes + 255) & ~(size_t)255;
    return p;
  };
  bf16* Wqh = (bf16*)take((size_t)WN * 2);
  bf16* Wql = (bf16*)take((size_t)WN * 2);
  bf16* Wkh = (bf16*)take((size_t)WN * 2);
  bf16* Wkl = (bf16*)take((size_t)WN * 2);
  bf16* Wvh = (bf16*)take((size_t)WN * 2);
  bf16* Wfh = (bf16*)take((size_t)WN * 2);
  bf16* Qh = (bf16*)take((size_t)8 * BD * 2);   // compacted per batch
  bf16* Ql = (bf16*)take((size_t)8 * BD * 2);
  bf16* Kh = (bf16*)take((size_t)8 * BD * 2);
  bf16* Kl = (bf16*)take((size_t)8 * BD * 2);
  bf16* VT = (bf16*)take((size_t)8 * BD * 2);   // [z][768][2048]
  bf16* P  = (bf16*)take((size_t)8 * N * N * 2);  // [z][2048][2048]
  float* rowsum = (float*)take((size_t)8 * N * sizeof(float));
  int* idx = (int*)take((size_t)8 * N * sizeof(int));
  int* cnt = (int*)take(64);
  // V (compact proj output) aliases the tail of P: dead before S-GEMM writes P
  bf16* V = (bf16*)((char*)P + (size_t)8 * N * N * 2 - (size_t)8 * BD * 2);
  bf16* merged = Qh;  // Qh dead after S-GEMM

  dim3 blk(256);

  compact_kernel<<<dim3(8), blk, 0, stream>>>(mask, idx, cnt);
  cvt4_kernel<<<dim3(288, 4), blk, 0, stream>>>(q_w, k_w, v_w, fc_w,
      Wqh, Wql, Wkh, Wkl, Wvh, Wfh, W8);
  hipMemsetAsync(rowsum, 0, (size_t)8 * N * sizeof(float), stream);
  bias_fill_kernel<<<dim3(12288), blk, 0, stream>>>((float*)d_out, fc_b);

  // Gathered projections over valid rows only (split for Q/K, single for V)
  gemm_nt<1, true, 1, true, false, true, false, false, false><<<dim3(6, 16, 8), blk, 0, stream>>>(
      query, nullptr, D, BD, Wqh, Wql, D, 0, Qh, Ql, D, BD, (int)D,
      q_b, nullptr, 0, idx, cnt);
  gemm_nt<1, true, 1, true, false, true, false, false, false><<<dim3(6, 16, 8), blk, 0, stream>>>(
      value, nullptr, D, BD, Wkh, Wkl, D, 0, Kh, Kl, D, BD, (int)D,
      k_b, nullptr, 0, idx, cnt);
  gemm_nt<1, false, 0, true, false, true, false, false, false><<<dim3(6, 16, 8), blk, 0, stream>>>(
      value, nullptr, D, BD, Wvh, nullptr, D, 0, V, nullptr, D, BD, (int)D,
      v_b, nullptr, 0, idx, cnt);
  transpose_kernel<<<dim3(32, 12, 8), blk, 0, stream>>>((const u16*)V, (u16*)VT, cnt);

  // P = exp(Qc Kc^T - 48) bf16 over compacted rows/cols, rowsums atomic
  gemm_nt<0, true, 3, false, false, false, false, false, true><<<dim3(16, 16, 8), blk, 0, stream>>>(
      Qh, Ql, D, BD, Kh, Kl, D, BD, P, nullptr, N, N * N, (int)D,
      nullptr, rowsum, N, nullptr, cnt);
  // merged_c = (P @ Vc) * (1/rowsum)   (ragged K = pad128(cnt))
  gemm_nt<0, false, 0, false, true, false, false, true, false><<<dim3(6, 16, 8), blk, 0, stream>>>(
      P, nullptr, N, N * N, VT, nullptr, N, BD, merged, nullptr, D, BD, 0,
      nullptr, rowsum, N, nullptr, cnt);
  // out rows (scattered) = merged_c @ fc_w^T + fc_b; masked rows already = fc_b
  gemm_nt<0, false, 2, true, false, false, true, false, false><<<dim3(6, 16, 8), blk, 0, stream>>>(
      merged, nullptr, D, BD, Wfh, nullptr, D, 0, d_out, nullptr, D, BD, (int)D,
      fc_b, nullptr, 0, idx, cnt);
}

// Round 6
// 439.355 us; speedup vs baseline: 1.7571x; 1.0381x over previous
//
#include <hip/hip_runtime.h>
#include <hip/hip_bf16.h>

using bf16 = __hip_bfloat16;
typedef __attribute__((ext_vector_type(4))) float f32x4;
typedef __attribute__((ext_vector_type(8))) __bf16 bf16x8;
typedef __attribute__((ext_vector_type(4))) unsigned int u32x4;
typedef unsigned short u16;

#define LOG2E 1.4426950408889634f
// fixed softmax shift: p = exp(s - 48) = exp2(s*log2e - 48*log2e)
#define SHIFT2 69.24936192747498f

__device__ __forceinline__ void gload_lds16(const void* g, void* l) {
  __builtin_amdgcn_global_load_lds((const __attribute__((address_space(1))) void*)g,
                                   (__attribute__((address_space(3))) void*)l, 16, 0, 0);
}

__device__ __forceinline__ bf16x8 lds_frag(const bf16* p) {
  u32x4 u = *(const u32x4*)p;
  return __builtin_bit_cast(bf16x8, u);
}

__device__ __forceinline__ u16 bf_bits(float v) {
  return __builtin_bit_cast(u16, __float2bfloat16(v));
}

struct GArgs {
  const void* Ah; const void* Al; long lda; long strideA;
  const bf16* Bh; const bf16* Bl; long ldb; long strideB;
  void* Ch; void* Cl; long ldc; long strideC;
  int K;
  const float* bias;
  float* rowsum; long rsStride;
  const int* idx; const int* cnt;
  // matrix set #2 (QK2 merged dispatch)
  const void* Ah2; const bf16* Bh2; const bf16* Bl2;
  void* Ch2; void* Cl2; const float* bias2;
};

// NT GEMM: C[m][n] = sum_k A[m][k]*B[n][k]. 128x128 tile, BK=32, 256 threads.
// Compacted 1D tile grid: per-z tile counts from cnt[], grid-stride over dense ids
// (fixes CU clustering from early-exit holes — R4 showed 2.4x loss).
// AMODE: 0 = A bf16 global via global_load_lds; 1 = A fp32 global, stage-convert in LDS
// SPLIT: hi/lo bf16 emulation of fp32 (3 MFMA passes)
// CMODE: 0 = bf16 C, 1 = bf16 pair (Ch,Cl), 2 = fp32 C,
//        3 = P-epilogue: bf16 exp(s-48), cols>=cnt -> 0, row sums -> rowsum (atomic)
// BIAS: += bias[n]. RSCALE (CMODE0): row *= 1/rowsum. MGATHER (AMODE1): A row via idx.
// CSCAT (CMODE2): C row scattered via idx, rows>=cnt skipped.
// SQUARE: n-tile count = Tz (else 6). RAGK: contraction K = Tz*128 (PV only!).
// NOTE (R5 bug): S-GEMM contraction is D=768 — SQUARE must NOT imply ragged K.
// QK2: virtual z = 16; vz>=8 uses matrix set #2.
template<int AMODE, bool SPLIT, int CMODE, bool BIAS, bool RSCALE,
         bool MGATHER, bool CSCAT, bool SQUARE, bool RAGK, bool QK2>
__global__ __launch_bounds__(256, 2) void gemm_nt(GArgs ga)
{
  const int tid = threadIdx.x;
  const int lane15 = tid & 15;
  const int quad = (tid >> 4) & 3;
  const int wave = tid >> 6;
  const int wm = (wave >> 1) * 64;
  const int wn = (wave & 1) * 64;

  constexpr int NZ = QK2 ? 16 : 8;
  constexpr int KW = SPLIT ? 64 : 32;
  __shared__ alignas(16) bf16 As[128 * KW];
  __shared__ alignas(16) bf16 Bs[128 * KW];
  __shared__ float rowacc[128];
  __shared__ int sT[8];
  __shared__ int sTz[NZ];

  if (tid < 8) sT[tid] = (ga.cnt[tid] + 127) >> 7;
  __syncthreads();
  if (tid < NZ) {
    const int Tm = sT[QK2 ? (tid & 7) : tid];
    sTz[tid] = SQUARE ? Tm * Tm : Tm * 6;
  }
  __syncthreads();
  int total = 0;
  #pragma unroll
  for (int i = 0; i < NZ; ++i) total += sTz[i];

  // AMODE 1 staging roles: thread t -> row t/2, half t&1
  const int arow = tid >> 1;
  const int ahalf = tid & 1;
  const int aflip = arow & 1;
  const int aswz = (arow >> 1) & 3;

  for (int t = blockIdx.x; t < total; t += gridDim.x) {
    // decompose dense tile id -> (vz, mt, nt)
    int vz = 0, rem = t;
    while (rem >= sTz[vz]) { rem -= sTz[vz]; ++vz; }
    const int z = QK2 ? (vz & 7) : vz;
    const int mat = QK2 ? (vz >> 3) : 0;
    const int Tm = sT[z];
    int mt, nt;
    if constexpr (SQUARE) { mt = rem / Tm; nt = rem - mt * Tm; }
    else                  { mt = rem / 6;  nt = rem - mt * 6; }
    const long m0 = (long)mt * 128;
    const long n0 = (long)nt * 128;
    const int cnt = ga.cnt[z];
    const int K = RAGK ? Tm * 128 : ga.K;   // FIXED: SQUARE no longer implies ragged K

    const bf16* Bh = (QK2 && mat) ? ga.Bh2 : ga.Bh;
    const bf16* Bl = (QK2 && mat) ? ga.Bl2 : ga.Bl;
    const bf16* Bbh = Bh + z * ga.strideB;
    const bf16* Bbl = SPLIT ? (Bl + z * ga.strideB) : nullptr;

    const bf16* Abh = nullptr; const bf16* Abl = nullptr;
    const float* Af = nullptr;
    {
      const void* Ahp = (QK2 && mat) ? ga.Ah2 : ga.Ah;
      if constexpr (AMODE == 0) {
        Abh = (const bf16*)Ahp + (long)z * ga.strideA;
        if constexpr (SPLIT) Abl = (const bf16*)ga.Al + (long)z * ga.strideA;
      } else {
        Af = (const float*)Ahp + (long)z * ga.strideA;
      }
    }
    long agrow = m0 + arow;
    if constexpr (AMODE == 1 && MGATHER) agrow = ga.idx[(long)z * 2048 + m0 + arow];

    f32x4 acc[4][4];
    #pragma unroll
    for (int i = 0; i < 4; ++i)
      #pragma unroll
      for (int j = 0; j < 4; ++j) acc[i][j] = (f32x4){0.f, 0.f, 0.f, 0.f};

    for (int k0 = 0; k0 < K; k0 += 32) {
      __syncthreads();
      // ---- B staging ----
      if constexpr (SPLIT) {
        #pragma unroll
        for (int r = 0; r < 4; ++r) {
          const int idx = r * 256 + tid, row = idx >> 3, slot = idx & 7;
          const int flip = row & 1, sw = (row >> 1) & 3;
          const int h = (slot >> 2) ^ flip, s = (slot & 3) ^ sw;
          const bf16* g = (h ? Bbl : Bbh) + (n0 + row) * ga.ldb + k0 + s * 8;
          gload_lds16(g, &Bs[idx * 8]);
        }
      } else {
        #pragma unroll
        for (int r = 0; r < 2; ++r) {
          const int idx = r * 256 + tid, row = idx >> 2, slot = idx & 3;
          const int sw = (row >> 1) & 3;
          gload_lds16(Bbh + (n0 + row) * ga.ldb + k0 + (slot ^ sw) * 8, &Bs[idx * 8]);
        }
      }
      // ---- A staging ----
      if constexpr (AMODE == 0) {
        if constexpr (SPLIT) {
          #pragma unroll
          for (int r = 0; r < 4; ++r) {
            const int idx = r * 256 + tid, row = idx >> 3, slot = idx & 7;
            const int flip = row & 1, sw = (row >> 1) & 3;
            const int h = (slot >> 2) ^ flip, s = (slot & 3) ^ sw;
            const bf16* g = (h ? Abl : Abh) + (m0 + row) * ga.lda + k0 + s * 8;
            gload_lds16(g, &As[idx * 8]);
          }
        } else {
          #pragma unroll
          for (int r = 0; r < 2; ++r) {
            const int idx = r * 256 + tid, row = idx >> 2, slot = idx & 3;
            const int sw = (row >> 1) & 3;
            gload_lds16(Abh + (m0 + row) * ga.lda + k0 + (slot ^ sw) * 8, &As[idx * 8]);
          }
        }
      } else {  // AMODE == 1 (optionally gathered)
        const float* src = Af + agrow * ga.lda + k0;
        #pragma unroll
        for (int ss = 0; ss < 2; ++ss) {
          const int s = ahalf * 2 + ss;
          float tv[8];
          *(f32x4*)tv       = *(const f32x4*)(src + s * 8);
          *(f32x4*)(tv + 4) = *(const f32x4*)(src + s * 8 + 4);
          u32x4 hi, lo;
          u16* ph = (u16*)&hi; u16* pl = (u16*)&lo;
          #pragma unroll
          for (int j = 0; j < 8; ++j) {
            bf16 hb = __float2bfloat16(tv[j]);
            ph[j] = __builtin_bit_cast(u16, hb);
            if constexpr (SPLIT) pl[j] = bf_bits(tv[j] - __bfloat162float(hb));
          }
          if constexpr (SPLIT) {
            const int sh = (aflip << 2) | (s ^ aswz);
            *(u32x4*)&As[arow * 64 + sh * 8] = hi;
            *(u32x4*)&As[arow * 64 + (sh ^ 4) * 8] = lo;
          } else {
            *(u32x4*)&As[arow * 32 + (s ^ aswz) * 8] = hi;
          }
        }
      }
      __syncthreads();

      const int swl = (lane15 >> 1) & 3;
      if constexpr (SPLIT) {
        const int eff = ((lane15 & 1) << 2) | (quad ^ swl);
        bf16x8 ah[4], al[4], bh[4], bl[4];
        #pragma unroll
        for (int tt = 0; tt < 4; ++tt) {
          const int ar = (wm + tt * 16 + lane15) * 64;
          const int br = (wn + tt * 16 + lane15) * 64;
          ah[tt] = lds_frag(&As[ar + eff * 8]);
          al[tt] = lds_frag(&As[ar + (eff ^ 4) * 8]);
          bh[tt] = lds_frag(&Bs[br + eff * 8]);
          bl[tt] = lds_frag(&Bs[br + (eff ^ 4) * 8]);
        }
        #pragma unroll
        for (int i = 0; i < 4; ++i)
          #pragma unroll
          for (int j = 0; j < 4; ++j) {
            acc[i][j] = __builtin_amdgcn_mfma_f32_16x16x32_bf16(ah[i], bh[j], acc[i][j], 0, 0, 0);
            acc[i][j] = __builtin_amdgcn_mfma_f32_16x16x32_bf16(al[i], bh[j], acc[i][j], 0, 0, 0);
            acc[i][j] = __builtin_amdgcn_mfma_f32_16x16x32_bf16(ah[i], bl[j], acc[i][j], 0, 0, 0);
          }
      } else {
        const int eff = quad ^ swl;
        bf16x8 ah[4], bh[4];
        #pragma unroll
        for (int tt = 0; tt < 4; ++tt) ah[tt] = lds_frag(&As[(wm + tt * 16 + lane15) * 32 + eff * 8]);
        #pragma unroll
        for (int tt = 0; tt < 4; ++tt) bh[tt] = lds_frag(&Bs[(wn + tt * 16 + lane15) * 32 + eff * 8]);
        #pragma unroll
        for (int i = 0; i < 4; ++i)
          #pragma unroll
          for (int j = 0; j < 4; ++j)
            acc[i][j] = __builtin_amdgcn_mfma_f32_16x16x32_bf16(ah[i], bh[j], acc[i][j], 0, 0, 0);
      }
    }

    // C/D layout: col = lane&15, row = quad*4 + reg   [measured m89/m91]
    const long crow0 = m0 + wm + quad * 4;
    const long ccol0 = n0 + wn + lane15;

    if constexpr (CMODE == 3) {
      // P = exp(s - 48) as bf16 (cols >= cnt -> 0), per-row sums -> rowsum (atomic)
      bf16* P = (bf16*)ga.Ch + (long)z * ga.strideC;
      __syncthreads();
      if (tid < 128) rowacc[tid] = 0.f;
      __syncthreads();
      bool keep[4];
      #pragma unroll
      for (int tn = 0; tn < 4; ++tn) keep[tn] = (ccol0 + tn * 16) < cnt;
      #pragma unroll
      for (int tm = 0; tm < 4; ++tm) {
        #pragma unroll
        for (int r = 0; r < 4; ++r) {
          const long row = crow0 + tm * 16 + r;
          float rsum = 0.f;
          #pragma unroll
          for (int tn = 0; tn < 4; ++tn) {
            float p = keep[tn] ? exp2f(fmaf(acc[tm][tn][r], LOG2E, -SHIFT2)) : 0.f;
            bf16 pb = __float2bfloat16(p);
            P[row * ga.ldc + ccol0 + tn * 16] = pb;
            rsum += __bfloat162float(pb);
          }
          atomicAdd(&rowacc[(int)(row - m0)], rsum);
        }
      }
      __syncthreads();
      if (tid < 128) atomicAdd(&ga.rowsum[z * ga.rsStride + m0 + tid], rowacc[tid]);
      continue;
    }

    const float* bias = (QK2 && mat) ? ga.bias2 : ga.bias;
    float bv[4] = {0.f, 0.f, 0.f, 0.f};
    if constexpr (BIAS) {
      #pragma unroll
      for (int tn = 0; tn < 4; ++tn) bv[tn] = bias[ccol0 + tn * 16];
    }
    if constexpr (CMODE == 2) {
      float* C = (float*)ga.Ch + (long)z * ga.strideC;
      #pragma unroll
      for (int tm = 0; tm < 4; ++tm) {
        #pragma unroll
        for (int r = 0; r < 4; ++r) {
          const long row = crow0 + tm * 16 + r;
          long orow = row;
          bool doStore = true;
          if constexpr (CSCAT) {
            doStore = row < cnt;
            orow = doStore ? (long)ga.idx[(long)z * 2048 + row] : 0;
          }
          if (doStore) {
            #pragma unroll
            for (int tn = 0; tn < 4; ++tn)
              C[orow * ga.ldc + ccol0 + tn * 16] = acc[tm][tn][r] + bv[tn];
          }
        }
      }
    } else if constexpr (CMODE == 1) {
      bf16* Ch = (bf16*)((QK2 && mat) ? ga.Ch2 : ga.Ch) + (long)z * ga.strideC;
      bf16* Cl = (bf16*)((QK2 && mat) ? ga.Cl2 : ga.Cl) + (long)z * ga.strideC;
      #pragma unroll
      for (int tm = 0; tm < 4; ++tm) {
        const long row = crow0 + tm * 16;
        #pragma unroll
        for (int tn = 0; tn < 4; ++tn) {
          const long col = ccol0 + tn * 16;
          #pragma unroll
          for (int r = 0; r < 4; ++r) {
            float val = acc[tm][tn][r] + bv[tn];
            bf16 h = __float2bfloat16(val);
            Ch[(row + r) * ga.ldc + col] = h;
            Cl[(row + r) * ga.ldc + col] = __float2bfloat16(val - __bfloat162float(h));
          }
        }
      }
    } else {
      bf16* Ch = (bf16*)ga.Ch + (long)z * ga.strideC;
      #pragma unroll
      for (int tm = 0; tm < 4; ++tm) {
        const long row = crow0 + tm * 16;
        float rm[4];
        #pragma unroll
        for (int r = 0; r < 4; ++r) {
          float f = 1.f;
          if constexpr (RSCALE) f = 1.0f / ga.rowsum[z * ga.rsStride + row + r];
          rm[r] = f;
        }
        #pragma unroll
        for (int tn = 0; tn < 4; ++tn) {
          const long col = ccol0 + tn * 16;
          #pragma unroll
          for (int r = 0; r < 4; ++r)
            Ch[(row + r) * ga.ldc + col] = __float2bfloat16((acc[tm][tn][r] + bv[tn]) * rm[r]);
        }
      }
    }
  }
}

// per-batch compaction: idx[z][0..cnt) = positions with mask!=0; tail filled with last valid
__global__ __launch_bounds__(256) void compact_kernel(
    const int* __restrict__ mask, int* __restrict__ idx, int* __restrict__ cnt)
{
  const int z = blockIdx.x, tid = threadIdx.x;
  const int* m = mask + (long)z * 2048;
  int* id = idx + (long)z * 2048;
  int v[8]; int c = 0;
  #pragma unroll
  for (int j = 0; j < 8; ++j) { v[j] = m[tid * 8 + j]; c += (v[j] != 0) ? 1 : 0; }
  __shared__ int sc[256];
  sc[tid] = c;
  __syncthreads();
  for (int off = 1; off < 256; off <<= 1) {
    int y = 0;
    if (tid >= off) y = sc[tid - off];
    __syncthreads();
    if (tid >= off) sc[tid] += y;
    __syncthreads();
  }
  int k = sc[tid] - c;
  #pragma unroll
  for (int j = 0; j < 8; ++j)
    if (v[j]) id[k++] = tid * 8 + j;
  __syncthreads();
  const int tot = sc[255];
  if (tid == 0) cnt[z] = tot;
  const int last = id[tot - 1];
  for (int i = tot + tid; i < 2048; i += 256) id[i] = last;
}

// all 4 weight conversions in one launch (y selects matrix)
__global__ __launch_bounds__(256) void cvt4_kernel(
    const float* __restrict__ qw, const float* __restrict__ kw,
    const float* __restrict__ vw, const float* __restrict__ fw,
    bf16* __restrict__ Wqh, bf16* __restrict__ Wql,
    bf16* __restrict__ Wkh, bf16* __restrict__ Wkl,
    bf16* __restrict__ Wvh, bf16* __restrict__ Wfh, int n8)
{
  const int i = blockIdx.x * 256 + threadIdx.x;
  if (i >= n8) return;
  const float* in; bf16* oh; bf16* ol = nullptr;
  switch (blockIdx.y) {
    case 0:  in = qw; oh = Wqh; ol = Wql; break;
    case 1:  in = kw; oh = Wkh; ol = Wkl; break;
    case 2:  in = vw; oh = Wvh; break;
    default: in = fw; oh = Wfh; break;
  }
  float tv[8];
  *(f32x4*)tv       = ((const f32x4*)in)[2 * i];
  *(f32x4*)(tv + 4) = ((const f32x4*)in)[2 * i + 1];
  u32x4 H, L;
  u16* ph = (u16*)&H; u16* pl = (u16*)&L;
  #pragma unroll
  for (int j = 0; j < 8; ++j) {
    bf16 hb = __float2bfloat16(tv[j]);
    ph[j] = __builtin_bit_cast(u16, hb);
    pl[j] = bf_bits(tv[j] - __bfloat162float(hb));
  }
  ((u32x4*)oh)[i] = H;
  if (ol) ((u32x4*)ol)[i] = L;
}

// d_out[row][col] = fc_b[col] for all rows (valid rows overwritten by fc GEMM)
__global__ __launch_bounds__(256) void bias_fill_kernel(
    float* __restrict__ out, const float* __restrict__ fc_b)
{
  const long i = (long)blockIdx.x * 256 + threadIdx.x;  // f32x4 index
  const int col4 = (int)(i % 192);
  ((f32x4*)out)[i] = *(const f32x4*)(fc_b + col4 * 4);
}

// per-batch 64x64-tile bf16 transpose: V[z][r][c] -> VT[z][c][r]; skips r0 >= pad128(cnt)
__global__ __launch_bounds__(256) void transpose_kernel(
    const u16* __restrict__ in, u16* __restrict__ out, const int* __restrict__ cnt)
{
  const long z = blockIdx.z;
  const long r0 = (long)blockIdx.x * 64, c0 = (long)blockIdx.y * 64;
  const int kb = (cnt[z] + 127) & ~127;
  if (r0 >= kb) return;
  __shared__ alignas(16) u16 t[64][72];
  const u16* inz = in + z * 2048 * 768;
  u16* outz = out + z * 768 * 2048;
  const int tid = threadIdx.x;
  const int rr = tid >> 3, cs = (tid & 7) * 8;
  #pragma unroll
  for (int i = 0; i < 2; ++i) {
    const int row = rr + i * 32;
    u32x4 v = *(const u32x4*)(inz + (r0 + row) * 768 + c0 + cs);
    *(u32x4*)&t[row][cs] = v;
  }
  __syncthreads();
  #pragma unroll
  for (int i = 0; i < 2; ++i) {
    const int oc = rr + i * 32;
    u32x4 o;
    u16* po = (u16*)&o;
    #pragma unroll
    for (int j = 0; j < 8; ++j) po[j] = t[cs + j][oc];
    *(u32x4*)(outz + (c0 + oc) * 2048 + r0 + cs) = o;
  }
}

extern "C" void kernel_launch(void* const* d_in, const int* in_sizes, int n_in,
                              void* d_out, int out_size, void* d_ws, size_t ws_size,
                              hipStream_t stream) {
  const float* query = (const float*)d_in[0];
  const float* value = (const float*)d_in[1];
  const int*   mask  = (const int*)d_in[2];
  const float* q_w   = (const float*)d_in[3];
  const float* q_b   = (const float*)d_in[4];
  const float* k_w   = (const float*)d_in[5];
  const float* k_b   = (const float*)d_in[6];
  const float* v_w   = (const float*)d_in[7];
  const float* v_b   = (const float*)d_in[8];
  const float* fc_w  = (const float*)d_in[9];
  const float* fc_b  = (const float*)d_in[10];

  const long N = 2048, D = 768;
  const long BD = N * D;          // per-batch row-block (2048x768)
  const int WN = (int)(D * D), W8 = WN / 8;

  char* wp = (char*)d_ws;
  auto take = [&](size_t bytes) {
    char* p = wp;
    wp += (bytes + 255) & ~(size_t)255;
    return p;
  };
  bf16* Wqh = (bf16*)take((size_t)WN * 2);
  bf16* Wql = (bf16*)take((size_t)WN * 2);
  bf16* Wkh = (bf16*)take((size_t)WN * 2);
  bf16* Wkl = (bf16*)take((size_t)WN * 2);
  bf16* Wvh = (bf16*)take((size_t)WN * 2);
  bf16* Wfh = (bf16*)take((size_t)WN * 2);
  bf16* Qh = (bf16*)take((size_t)8 * BD * 2);   // compacted per batch
  bf16* Ql = (bf16*)take((size_t)8 * BD * 2);
  bf16* Kh = (bf16*)take((size_t)8 * BD * 2);
  bf16* Kl = (bf16*)take((size_t)8 * BD * 2);
  bf16* VT = (bf16*)take((size_t)8 * BD * 2);   // [z][768][2048]
  bf16* P  = (bf16*)take((size_t)8 * N * N * 2);  // [z][2048][2048]
  float* rowsum = (float*)take((size_t)8 * N * sizeof(float));
  int* idx = (int*)take((size_t)8 * N * sizeof(int));
  int* cnt = (int*)take(64);
  // V (compact proj output) aliases the tail of P: dead before S-GEMM writes P
  bf16* V = (bf16*)((char*)P + (size_t)8 * N * N * 2 - (size_t)8 * BD * 2);
  bf16* merged = Qh;  // Qh dead after S-GEMM

  dim3 blk(256);
  dim3 g512(512);

  compact_kernel<<<dim3(8), blk, 0, stream>>>(mask, idx, cnt);
  cvt4_kernel<<<dim3(288, 4), blk, 0, stream>>>(q_w, k_w, v_w, fc_w,
      Wqh, Wql, Wkh, Wkl, Wvh, Wfh, W8);
  hipMemsetAsync(rowsum, 0, (size_t)8 * N * sizeof(float), stream);
  bias_fill_kernel<<<dim3(12288), blk, 0, stream>>>((float*)d_out, fc_b);

  GArgs a{};
  a.idx = idx; a.cnt = cnt; a.rowsum = rowsum; a.rsStride = N;

  // merged Q+K projections (split, gathered rows): vz<8 -> query@Wq -> Qh/Ql,
  // vz>=8 -> value@Wk -> Kh/Kl
  a.Ah = query; a.Al = nullptr; a.lda = D; a.strideA = BD;
  a.Bh = Wqh; a.Bl = Wql; a.ldb = D; a.strideB = 0;
  a.Ch = Qh; a.Cl = Ql; a.ldc = D; a.strideC = BD;
  a.K = (int)D; a.bias = q_b;
  a.Ah2 = value; a.Bh2 = Wkh; a.Bl2 = Wkl; a.Ch2 = Kh; a.Cl2 = Kl; a.bias2 = k_b;
  gemm_nt<1, true, 1, true, false, true, false, false, false, true>
      <<<g512, blk, 0, stream>>>(a);

  // V projection (single, gathered)
  a.Ah = value; a.Bh = Wvh; a.Bl = nullptr;
  a.Ch = V; a.Cl = nullptr; a.bias = v_b;
  gemm_nt<1, false, 0, true, false, true, false, false, false, false>
      <<<g512, blk, 0, stream>>>(a);
  transpose_kernel<<<dim3(32, 12, 8), blk, 0, stream>>>((const u16*)V, (u16*)VT, cnt);

  // P = exp(Qc Kc^T - 48) bf16, rowsums atomic (square tile space, K = D)
  a.Ah = Qh; a.Al = Ql; a.lda = D; a.strideA = BD;
  a.Bh = Kh; a.Bl = Kl; a.ldb = D; a.strideB = BD;
  a.Ch = P; a.Cl = nullptr; a.ldc = N; a.strideC = N * N;
  a.K = (int)D; a.bias = nullptr;
  gemm_nt<0, true, 3, false, false, false, false, true, false, false>
      <<<g512, blk, 0, stream>>>(a);

  // merged_c = (P @ Vc) * (1/rowsum)   (ragged K = Tz*128)
  a.Ah = P; a.Al = nullptr; a.lda = N; a.strideA = N * N;
  a.Bh = VT; a.Bl = nullptr; a.ldb = N; a.strideB = BD;
  a.Ch = merged; a.Cl = nullptr; a.ldc = D; a.strideC = BD;
  gemm_nt<0, false, 0, false, true, false, false, false, true, false>
      <<<g512, blk, 0, stream>>>(a);

  // out rows (scattered) = merged_c @ fc_w^T + fc_b; masked rows already = fc_b
  a.Ah = merged; a.lda = D; a.strideA = BD;
  a.Bh = Wfh; a.Bl = nullptr; a.ldb = D; a.strideB = 0;
  a.Ch = d_out; a.Cl = nullptr; a.ldc = D; a.strideC = BD;
  a.K = (int)D; a.bias = fc_b;
  gemm_nt<0, false, 2, true, false, false, true, false, false, false>
      <<<g512, blk, 0, stream>>>(a);
}